// Round 10
// baseline (539.809 us; speedup 1.0000x reference)
//
#include <hip/hip_runtime.h>
#include <stdint.h>

// AR(12) rollout: 12 sequential GEMMs of [B=128 x K=24576] x [K x N=2048].
// R9 = R8 + BK 64->128 (6 phases): stage issued a FULL compute phase ahead
// (~1300 cyc) now covers L3 latency of the 32 KB B-tile; same 2-buffer /
// 1-barrier-per-phase schedule. fp16 partials (L2-resident), fp16 single-
// product numerics with exact pow2 per-slot scaling (R4-R8 proven).

typedef _Float16 f16x8 __attribute__((ext_vector_type(8)));
typedef float    f32x4 __attribute__((ext_vector_type(4)));

#define B_ 128
#define N_ 2048
#define P_ 12
#define K_ (P_*N_)          // 24576
#define KSPLIT 32
#define KCH (K_/KSPLIT)     // 768
#define NPHASE (KCH/128)    // 6 phases of BK=128
#define NTILES 16           // BN=128
#define NKP (K_/64)         // 384 BK64 W-tiles per nt column

#define WPK_BYTES   ((size_t)NTILES*NKP*16384) // 100,663,296 (fp16, tiled)
#define H_SLOT_BYTES ((size_t)B_*N_*2)         // 524,288 per window slot (fp16)
#define H_BYTES     (23*H_SLOT_BYTES)          // 12,058,624
#define PART_BYTES  ((size_t)KSPLIT*B_*N_*2)   // 16,777,216 (fp16)
#define WS_NEEDED   (WPK_BYTES + H_BYTES + PART_BYTES)   // ~130 MB

// Scale exponents for y_{t+1} (t=0..10): e = round(7.29 + 5.50*t) from the
// variance recursion sigma(y_1)=sqrt(24576), growth sqrt(2048) per step.
__device__ __constant__ int E_TAB[11] = {7, 13, 18, 24, 29, 35, 40, 46, 51, 57, 62};

__device__ __forceinline__ int e_of_slot(int g) {   // g = global slot index 0..22
    return (g < 12) ? 0 : E_TAB[g - 12];
}
__device__ __forceinline__ float pow2f(int e) {      // exact 2^e, |e| < 127
    return __uint_as_float((uint32_t)(127 + e) << 23);
}

union F16x8 { _Float16 h[8]; uint4 q; };
union F16x4v { _Float16 h[4]; uint2 q; };

// ---- H (window) layout: [slot][kblk=k/32][ko=(k%32)/8][b][8 elems] fp16 ----
// A-fragments read per-lane from global: lanes 0..15 (consecutive b) hit a
// contiguous 256B run; 4 ko-groups at stride 2048 -> 4x256B per instruction.
__device__ __forceinline__ uint32_t h_off(int slot, int b, int k) {
    return (uint32_t)slot * (uint32_t)H_SLOT_BYTES
         + (uint32_t)(k >> 5) * 8192u + (uint32_t)(((k >> 3) & 3) << 11)
         + (uint32_t)(b << 4) + (uint32_t)((k & 7) << 1);
}

// ---- Wp (B) layout: tile(nt, pk) = 16 KB covering BK=64 x BN=128 ----
// byte(ksub,c,ko) = (ksub&1)*8192 + ((c*64 + ko*16) ^ ((c&7)<<4)); consecutive
// pk tiles are contiguous -> a BK=128 phase stages 32 KB linearly.
__device__ __forceinline__ size_t w_tile_base(int nt, int pk) {
    return ((size_t)nt * NKP + (size_t)pk) * 16384;
}

// ---------------- prep: x->H (blocks 0..127), W->Wp (128..6271) ----------------
__global__ void prep_all(const float* __restrict__ x, const float* __restrict__ W,
                         char* __restrict__ Wp, char* __restrict__ H)
{
    __shared__ float tile[128][68];   // +4 pad, 34.8 KB
    int bid = blockIdx.x, t = threadIdx.x;
    if (bid < 128) {
        int tg = bid * 256 + t;                 // 32768 threads: (b, n-octet)
        int b = tg >> 8;
        int n0 = (tg & 255) << 3;
        const float4* s4 = (const float4*)(x + ((size_t)b * N_ + n0) * P_);
        float4 tmp[24];
        #pragma unroll
        for (int i2 = 0; i2 < 24; ++i2) tmp[i2] = s4[i2];
        #pragma unroll
        for (int p = 0; p < 12; ++p) {
            F16x8 o;
            #pragma unroll
            for (int q = 0; q < 8; ++q) {
                int fi = q * 12 + p;            // compile-time constant
                float4 blk = tmp[fi >> 2];
                float f = ((fi & 3) == 0) ? blk.x : ((fi & 3) == 1) ? blk.y : ((fi & 3) == 2) ? blk.z : blk.w;
                o.h[q] = (_Float16)f;
            }
            *(uint4*)(H + h_off(p, b, n0)) = o.q;
        }
        return;
    }
    int u = bid - 128;                          // 0..6143 = 16 nt x 384 pk
    int nt = u / NKP, pk = u % NKP;
    int i  = pk >> 5;                           // W slice 0..11
    int k0 = (pk & 31) << 6;                    // k-in-slice
    int j0 = nt << 7;
    #pragma unroll
    for (int pass = 0; pass < 8; ++pass) {      // coalesced fp32 reads along k
        int jl = pass * 16 + (t >> 4);
        int kq = (t & 15) * 4;
        float4 v = *(const float4*)(W + ((size_t)i * N_ + (j0 + jl)) * N_ + k0 + kq);
        tile[jl][kq + 0] = v.x; tile[jl][kq + 1] = v.y;
        tile[jl][kq + 2] = v.z; tile[jl][kq + 3] = v.w;
    }
    __syncthreads();
    int ksub = t >> 7, c = t & 127;
    char* base = Wp + w_tile_base(nt, pk) + (ksub << 13);
    #pragma unroll
    for (int ko = 0; ko < 4; ++ko) {
        F16x8 o;
        #pragma unroll
        for (int q = 0; q < 8; ++q) o.h[q] = (_Float16)tile[c][ksub * 32 + ko * 8 + q];
        uint32_t off = (uint32_t)((c << 6) + (ko << 4)) ^ (uint32_t)((c & 7) << 4);
        *(uint4*)(base + off) = o.q;
    }
}

// ---------------- per-step GEMM: partial[ks][b][j] (fp16, chunk-scale domain) ----------------
// grid 512 = 16 ntiles x 32 ks (bid%8 == ks%8 -> A-chunk sharers on one XCD).
// 4 waves as 2x2; wave tile 64x64; block tile 128x128; BK=128, 6 phases,
// 64 KB LDS (B only), 2 blocks/CU; A per-lane from L2 prefetched a phase ahead.
__global__ __launch_bounds__(256, 2) void gemm_step(
        const char* __restrict__ Wp, const char* __restrict__ H,
        _Float16* __restrict__ partial, int st)
{
    __shared__ alignas(16) char ldsB[2][32768];     // [buf][BK=128 x BN=128 fp16]
    const int tid  = threadIdx.x;
    const int lane = tid & 63;
    const int wv   = tid >> 6;                      // 0..3
    const int wr   = wv >> 1;                       // M half
    const int wc   = wv & 1;                        // N half
    const int bid  = blockIdx.x;
    const int ks    = bid % KSPLIT;
    const int ntile = bid / KSPLIT;                 // 0..15
    const int jbase = (ntile << 7) + (wc << 6) + (lane & 15);   // + nf*16
    const int ko   = lane >> 4;                     // k-octet 0..3
    const int kbase = ks * KCH;
    const int pk0  = kbase >> 6;                    // first BK64 W-tile of chunk

    // B-fragment byte offsets inside one 8KB ksub-half (R1-R8 proven swizzle)
    uint32_t boff[4];
    #pragma unroll
    for (int nf = 0; nf < 4; ++nf) {
        int c = (wc << 6) + (nf << 4) + (lane & 15);
        boff[nf] = (uint32_t)((c << 6) + (ko << 4)) ^ (uint32_t)((c & 7) << 4);
    }

    auto stage = [&](int buf, int ph) {             // 32 KB linear global->LDS
        const char* src = Wp + w_tile_base(ntile, pk0 + (ph << 1));
        #pragma unroll
        for (int j = 0; j < 8; ++j) {
            uint32_t o = (uint32_t)(j << 12) + (uint32_t)(tid << 4);
            __builtin_amdgcn_global_load_lds(
                (const __attribute__((address_space(1))) void*)(src + o),
                (__attribute__((address_space(3))) void*)&ldsB[buf][(j << 12) + (wv << 10)], 16, 0, 0);
        }
    };
    auto loadA = [&](int ph, f16x8 a[4][4]) {       // per-lane from L2, coalesced
        #pragma unroll
        for (int ksub = 0; ksub < 4; ++ksub) {
            int kg = kbase + (ph << 7) + (ksub << 5);
            const char* sb = H + (size_t)(st + (kg >> 11)) * H_SLOT_BYTES
                           + (uint32_t)(((kg & 2047) >> 5) << 13) + (uint32_t)(ko << 11);
            #pragma unroll
            for (int m = 0; m < 4; ++m) {
                int brow = (wr << 6) + (m << 4) + (lane & 15);
                a[ksub][m] = *(const f16x8*)(sb + (brow << 4));
            }
        }
    };

    f32x4 acc[4][4];
    #pragma unroll
    for (int m = 0; m < 4; ++m)
        #pragma unroll
        for (int n = 0; n < 4; ++n) acc[m][n] = (f32x4){0.f, 0.f, 0.f, 0.f};

    f16x8 a[4][4];
    loadA(0, a);
    stage(0, 0);
    __syncthreads();                                // drains stage (and loadA)

    int cur_e = e_of_slot(st + (kbase >> 11));
    #pragma unroll 1
    for (int ph = 0; ph < NPHASE; ++ph) {
        // exact pow2 domain change at window-slot boundary (wave-uniform;
        // 2048 % 128 == 0 so boundaries align with phase starts)
        int e_new = e_of_slot(st + ((kbase + (ph << 7)) >> 11));
        if (e_new != cur_e) {
            float f = pow2f(cur_e - e_new);
            #pragma unroll
            for (int m = 0; m < 4; ++m)
                #pragma unroll
                for (int n = 0; n < 4; ++n) acc[m][n] *= f;
            cur_e = e_new;
        }
        if (ph + 1 < NPHASE) stage((ph & 1) ^ 1, ph + 1);   // full phase ahead
        f16x8 an[4][4];
        if (ph + 1 < NPHASE) loadA(ph + 1, an);             // L2, hides under MFMA
        const char* lb = &ldsB[ph & 1][0];
        #pragma unroll
        for (int ksub = 0; ksub < 4; ++ksub) {
            f16x8 bf[4];
            #pragma unroll
            for (int nf = 0; nf < 4; ++nf)
                bf[nf] = *(const f16x8*)(lb + (ksub << 13) + boff[nf]);
            #pragma unroll
            for (int m = 0; m < 4; ++m)
                #pragma unroll
                for (int nf = 0; nf < 4; ++nf)
                    acc[m][nf] = __builtin_amdgcn_mfma_f32_16x16x32_f16(a[ksub][m], bf[nf], acc[m][nf], 0, 0, 0);
        }
        #pragma unroll
        for (int ksub = 0; ksub < 4; ++ksub)
            #pragma unroll
            for (int m = 0; m < 4; ++m) a[ksub][m] = an[ksub][m];
        __syncthreads();
    }

    // C/D layout (verified R0-R8): col = lane&15, row = (lane>>4)*4 + reg
    const int r0 = (lane >> 4) << 2;
    _Float16* pb = partial + ((size_t)ks * B_ + (wr << 6) + r0) * N_ + jbase;
    #pragma unroll
    for (int m = 0; m < 4; ++m)
        #pragma unroll
        for (int n = 0; n < 4; ++n)
            #pragma unroll
            for (int r = 0; r < 4; ++r)
                pb[(size_t)(m * 16 + r) * N_ + n * 16] = (_Float16)acc[m][n][r];
}

// ---------------- reduce 32 fp16 partials -> y; emit output + next window slot ----------------
__global__ void reduce_step(const _Float16* __restrict__ partial, float* __restrict__ out,
                            char* __restrict__ H, int t)
{
    int tid = blockIdx.x * 256 + threadIdx.x;   // 65536 threads: (b, n-quad)
    int b = tid >> 9;
    int n0 = (tid & 511) << 2;
    float s0 = 0.f, s1 = 0.f, s2 = 0.f, s3 = 0.f;
    #pragma unroll 4
    for (int c = 0; c < KSPLIT; ++c) {          // chunk scale = e of its LAST slot
        float sc = pow2f(e_of_slot(t + ((c * KCH + (KCH - 64)) >> 11)));
        F16x4v p;
        p.q = *(const uint2*)(partial + ((size_t)c * B_ + b) * N_ + n0);
        s0 += (float)p.h[0] * sc; s1 += (float)p.h[1] * sc;
        s2 += (float)p.h[2] * sc; s3 += (float)p.h[3] * sc;
    }
    float* ob = out + ((size_t)b * N_ + n0) * P_ + t;
    ob[0 * P_] = s0; ob[1 * P_] = s1; ob[2 * P_] = s2; ob[3 * P_] = s3;
    if (t < 11) {                                // y_12 never re-enters the window
        float ds = pow2f(-E_TAB[t]);             // store next slot scaled by 2^-e
        F16x4v o;
        o.h[0] = (_Float16)(s0 * ds); o.h[1] = (_Float16)(s1 * ds);
        o.h[2] = (_Float16)(s2 * ds); o.h[3] = (_Float16)(s3 * ds);
        *(uint2*)(H + h_off(12 + t, b, n0)) = o.q;   // 8B contiguous in this layout
    }
}

// ---------------- insurance: naive fp32 path if workspace is too small ----------------
__global__ void naive_step(const float* __restrict__ x, const float* __restrict__ W,
                           float* __restrict__ out, int t)
{
    int tid = blockIdx.x * 256 + threadIdx.x;   // 262144 threads: (b, j)
    int b = tid >> 11;
    int j = tid & (N_ - 1);
    float acc = 0.f;
    for (int i = 0; i < 12; ++i) {
        int g = t + i;
        const float* src = (g < 12) ? (x   + (size_t)b * (N_ * 12) + g)
                                    : (out + (size_t)b * (N_ * 12) + (g - 12));
        const float* wr = W + ((size_t)i * N_ + j) * N_;
        for (int k = 0; k < N_; ++k)
            acc += wr[k] * src[(size_t)k * 12];
    }
    out[((size_t)b * N_ + j) * 12 + t] = acc;
}

extern "C" void kernel_launch(void* const* d_in, const int* in_sizes, int n_in,
                              void* d_out, int out_size, void* d_ws, size_t ws_size,
                              hipStream_t stream)
{
    const float* x = (const float*)d_in[0];
    const float* W = (const float*)d_in[1];
    float* out = (float*)d_out;

    if (ws_size < WS_NEEDED) {                  // fallback: correct but slow
        for (int t = 0; t < 12; ++t)
            naive_step<<<1024, 256, 0, stream>>>(x, W, out, t);
        return;
    }

    char* ws = (char*)d_ws;
    char* Wp = ws;
    char* H  = Wp + WPK_BYTES;
    _Float16* partial = (_Float16*)(H + H_BYTES);

    prep_all<<<6272, 256, 0, stream>>>(x, W, Wp, H);
    for (int t = 0; t < 12; ++t) {
        gemm_step<<<512, 256, 0, stream>>>(Wp, H, partial, t);
        reduce_step<<<256, 256, 0, stream>>>(partial, out, H, t);
    }
}

// Round 11
// 493.828 us; speedup vs baseline: 1.0931x; 1.0931x over previous
//
#include <hip/hip_runtime.h>
#include <stdint.h>

// AR(12) rollout, feed-forward/feedback decomposition.
// y_{t+1} = F_{t+1} + sum_{j=0..t-1} W_{12-t+j} . y_{j+1}
// F (78 x-slot products) computed in ONE MFMA-bound launch (W read ~once from
// L3 with XCD clustering); sequential steps only do the triangular feedback
// (K = t*2048), cutting per-step W-L3 traffic. Single-slot K-chunks -> no acc
// rescale. fp16 single-product numerics + exact pow2 slot scales (R4-R8).

typedef _Float16 f16x8 __attribute__((ext_vector_type(8)));
typedef float    f32x4 __attribute__((ext_vector_type(4)));

#define B_ 128
#define N_ 2048
#define P_ 12
#define K_ (P_*N_)          // 24576
#define NT 16               // N-tiles of 128
#define NKP (K_/64)         // 384 BK64 W-tiles per nt column

#define WPK_BYTES    ((size_t)NT*NKP*16384)    // 100,663,296 (fp16, tiled)
#define H_SLOT_BYTES ((size_t)B_*N_*2)         // 524,288 per window slot
#define H_BYTES      (23*H_SLOT_BYTES)         // 12,058,624
#define CH_BYTES     ((size_t)B_*N_*2)         // one partial chunk (fp16)
#define PF_BYTES     (78*CH_BYTES)             // 40,894,464
#define PFB_BYTES    (44*CH_BYTES)             // 23,068,672
#define WS_NEEDED    (WPK_BYTES + H_BYTES + PF_BYTES + PFB_BYTES)  // ~177 MB

// Scale exponents for y_{t+1} (t=0..10): e = round(7.29 + 5.50*t) from the
// variance recursion sigma(y_1)=sqrt(24576), growth sqrt(2048) per step.
__device__ __constant__ int E_TAB[11] = {7, 13, 18, 24, 29, 35, 40, 46, 51, 57, 62};

__device__ __forceinline__ float pow2f(int e) {      // exact 2^e, |e| < 127
    return __uint_as_float((uint32_t)(127 + e) << 23);
}

union F16x8 { _Float16 h[8]; uint4 q; };
union F16x4v { _Float16 h[4]; uint2 q; };

// ---- H (window) layout: [slot][kblk=k/32][ko=(k%32)/8][b][8 elems] fp16 ----
__device__ __forceinline__ uint32_t h_off(int slot, int b, int k) {
    return (uint32_t)slot * (uint32_t)H_SLOT_BYTES
         + (uint32_t)(k >> 5) * 8192u + (uint32_t)(((k >> 3) & 3) << 11)
         + (uint32_t)(b << 4) + (uint32_t)((k & 7) << 1);
}
// ---- Wp (B) layout: tile(nt, pk) = 16 KB covering BK=64 x BN=128 (proven) ----
__device__ __forceinline__ size_t w_tile_base(int nt, int pk) {
    return ((size_t)nt * NKP + (size_t)pk) * 16384;
}

// ---------------- prep: x->H (blocks 0..127), W->Wp (128..6271) ----------------
__global__ void prep_all(const float* __restrict__ x, const float* __restrict__ W,
                         char* __restrict__ Wp, char* __restrict__ H)
{
    __shared__ float tile[128][68];   // +4 pad
    int bid = blockIdx.x, t = threadIdx.x;
    if (bid < 128) {
        int tg = bid * 256 + t;                 // 32768 threads: (b, n-octet)
        int b = tg >> 8;
        int n0 = (tg & 255) << 3;
        const float4* s4 = (const float4*)(x + ((size_t)b * N_ + n0) * P_);
        float4 tmp[24];
        #pragma unroll
        for (int i2 = 0; i2 < 24; ++i2) tmp[i2] = s4[i2];
        #pragma unroll
        for (int p = 0; p < 12; ++p) {
            F16x8 o;
            #pragma unroll
            for (int q = 0; q < 8; ++q) {
                int fi = q * 12 + p;            // compile-time constant
                float4 blk = tmp[fi >> 2];
                float f = ((fi & 3) == 0) ? blk.x : ((fi & 3) == 1) ? blk.y : ((fi & 3) == 2) ? blk.z : blk.w;
                o.h[q] = (_Float16)f;
            }
            *(uint4*)(H + h_off(p, b, n0)) = o.q;
        }
        return;
    }
    int u = bid - 128;                          // 0..6143 = 16 nt x 384 pk
    int nt = u / NKP, pk = u % NKP;
    int i  = pk >> 5;                           // W slice 0..11
    int k0 = (pk & 31) << 6;                    // k-in-slice
    int j0 = nt << 7;
    #pragma unroll
    for (int pass = 0; pass < 8; ++pass) {      // coalesced fp32 reads along k
        int jl = pass * 16 + (t >> 4);
        int kq = (t & 15) * 4;
        float4 v = *(const float4*)(W + ((size_t)i * N_ + (j0 + jl)) * N_ + k0 + kq);
        tile[jl][kq + 0] = v.x; tile[jl][kq + 1] = v.y;
        tile[jl][kq + 2] = v.z; tile[jl][kq + 3] = v.w;
    }
    __syncthreads();
    int ksub = t >> 7, c = t & 127;
    char* base = Wp + w_tile_base(nt, pk) + (ksub << 13);
    #pragma unroll
    for (int ko = 0; ko < 4; ++ko) {
        F16x8 o;
        #pragma unroll
        for (int q = 0; q < 8; ++q) o.h[q] = (_Float16)tile[c][ksub * 32 + ko * 8 + q];
        uint32_t off = (uint32_t)((c << 6) + (ko << 4)) ^ (uint32_t)((c & 7) << 4);
        *(uint4*)(base + off) = o.q;
    }
}

// ---------------- shared GEMM body: one K-chunk of one slot-product ----------------
// B (W tiles pk0..pk0+nph-1) staged 16KB/phase via global_load_lds (R5-R8
// proven); A per-lane from H slot (L2/L3-resident). NO scale logic here.
__device__ __forceinline__ void gemm_body(
        const char* __restrict__ Wp, const char* __restrict__ H,
        _Float16* __restrict__ part, char* ldsB,
        int nt, int pk0, int slot, int k0, int nph)
{
    const int tid  = threadIdx.x;
    const int lane = tid & 63;
    const int wv   = tid >> 6;
    const int wr   = wv >> 1;                   // M half
    const int wc   = wv & 1;                    // N half
    const int l15  = lane & 15;
    const int ko   = lane >> 4;                 // k-octet 0..3
    const int jbase = (nt << 7) + (wc << 6) + l15;

    uint32_t boff[4];
    #pragma unroll
    for (int nf = 0; nf < 4; ++nf) {
        int c = (wc << 6) + (nf << 4) + l15;
        boff[nf] = (uint32_t)((c << 6) + (ko << 4)) ^ (uint32_t)((c & 7) << 4);
    }

    auto stage = [&](int buf, int ph) {         // 16 KB linear global->LDS
        const char* src = Wp + w_tile_base(nt, pk0 + ph);
        #pragma unroll
        for (int j = 0; j < 4; ++j) {
            uint32_t o = (uint32_t)(j << 12) + (uint32_t)(tid << 4);
            __builtin_amdgcn_global_load_lds(
                (const __attribute__((address_space(1))) void*)(src + o),
                (__attribute__((address_space(3))) void*)(ldsB + buf * 16384 + (j << 12) + (wv << 10)), 16, 0, 0);
        }
    };
    auto loadA = [&](int ph, f16x8 a[2][4]) {   // per-lane, coalesced 256B runs
        #pragma unroll
        for (int ksub = 0; ksub < 2; ++ksub) {
            int k = k0 + (ph << 6) + (ksub << 5);
            const char* sb = H + (size_t)slot * H_SLOT_BYTES
                           + (uint32_t)((k >> 5) << 13) + (uint32_t)(ko << 11);
            #pragma unroll
            for (int m = 0; m < 4; ++m) {
                int brow = (wr << 6) + (m << 4) + l15;
                a[ksub][m] = *(const f16x8*)(sb + (brow << 4));
            }
        }
    };

    f32x4 acc[4][4];
    #pragma unroll
    for (int m = 0; m < 4; ++m)
        #pragma unroll
        for (int n = 0; n < 4; ++n) acc[m][n] = (f32x4){0.f, 0.f, 0.f, 0.f};

    f16x8 a[2][4];
    loadA(0, a);
    stage(0, 0);
    __syncthreads();

    #pragma unroll 1
    for (int ph = 0; ph < nph; ++ph) {
        if (ph + 1 < nph) stage((ph & 1) ^ 1, ph + 1);
        const char* lb = ldsB + (ph & 1) * 16384;
        f16x8 bf[2][4];
        #pragma unroll
        for (int ksub = 0; ksub < 2; ++ksub)
            #pragma unroll
            for (int nf = 0; nf < 4; ++nf)
                bf[ksub][nf] = *(const f16x8*)(lb + (ksub << 13) + boff[nf]);
        f16x8 an[2][4];
        if (ph + 1 < nph) loadA(ph + 1, an);
        #pragma unroll
        for (int ksub = 0; ksub < 2; ++ksub)
            #pragma unroll
            for (int m = 0; m < 4; ++m)
                #pragma unroll
                for (int nf = 0; nf < 4; ++nf)
                    acc[m][nf] = __builtin_amdgcn_mfma_f32_16x16x32_f16(a[ksub][m], bf[ksub][nf], acc[m][nf], 0, 0, 0);
        #pragma unroll
        for (int ksub = 0; ksub < 2; ++ksub)
            #pragma unroll
            for (int m = 0; m < 4; ++m) a[ksub][m] = an[ksub][m];
        __syncthreads();
    }

    // C/D layout (verified R0-R9): col = lane&15, row = (lane>>4)*4 + reg
    const int r0 = (lane >> 4) << 2;
    _Float16* pb = part + ((size_t)((wr << 6) + r0)) * N_ + jbase;
    #pragma unroll
    for (int m = 0; m < 4; ++m)
        #pragma unroll
        for (int n = 0; n < 4; ++n)
            #pragma unroll
            for (int r = 0; r < 4; ++r)
                pb[(size_t)(m * 16 + r) * N_ + n * 16] = (_Float16)acc[m][n][r];
}

// ---------------- F: all 78 x-slot products, one launch ----------------
// grid 1248 = 78 products x 16 nt; bid%8 == nt%8 -> same-(nt,j) W-tile
// sharers cluster on one XCD (L2 reuse). Product (t,j): W_j . x_{t+j}.
__global__ __launch_bounds__(256, 2) void gemm_F(
        const char* __restrict__ Wp, const char* __restrict__ H,
        _Float16* __restrict__ pF)
{
    __shared__ alignas(16) char ldsB[2 * 16384];
    int p = blockIdx.x >> 4, nt = blockIdx.x & 15;
    int j = 0, t = p;                           // decode j-major enumeration
    #pragma unroll 1
    for (int jj = 0; jj < 12; ++jj) {
        int cnt = 12 - jj;
        if (t < cnt) { j = jj; break; }
        t -= cnt;
    }
    int idx = t * 12 - t * (t - 1) / 2 + j;     // t-major storage for reduce
    gemm_body(Wp, H, pF + (size_t)idx * (CH_BYTES / 2), ldsB,
              nt, j * 32, t + j, 0, 32);
}

// ---------------- feedback step t: K = t*2048 over y-slots, 4t chunks ----------------
// grid 64t = 4t chunks x 16 nt. Chunk c: j=c>>2 (y-slot 12+j), sub=c&3.
__global__ __launch_bounds__(256, 2) void gemm_FB(
        const char* __restrict__ Wp, const char* __restrict__ H,
        _Float16* __restrict__ pFB, int t)
{
    __shared__ alignas(16) char ldsB[2 * 16384];
    int c = blockIdx.x >> 4, nt = blockIdx.x & 15;
    int j = c >> 2, sub = c & 3;
    int i = 12 - t + j;                         // W slice index in window
    gemm_body(Wp, H, pFB + (size_t)c * (CH_BYTES / 2), ldsB,
              nt, i * 32 + sub * 8, 12 + j, sub * 512, 8);
}

// ---------------- reduce step t: y_{t+1} = sum F-chunks + scaled fb-chunks ----------------
__global__ void reduce_step(const _Float16* __restrict__ pF, const _Float16* __restrict__ pFB,
                            float* __restrict__ out, char* __restrict__ H, int t)
{
    int tid = blockIdx.x * 256 + threadIdx.x;   // 65536 threads: (b, n-quad)
    int b = tid >> 9;
    int n0 = (tid & 511) << 2;
    const size_t eo = (size_t)b * N_ + n0;
    float s0 = 0.f, s1 = 0.f, s2 = 0.f, s3 = 0.f;
    int baseT = t * 12 - t * (t - 1) / 2;
    int nF = 12 - t;
    #pragma unroll 4
    for (int f = 0; f < nF; ++f) {              // F chunks: scale 1 (x domain)
        F16x4v p;
        p.q = *(const uint2*)(pF + (size_t)(baseT + f) * (CH_BYTES / 2) + eo);
        s0 += (float)p.h[0]; s1 += (float)p.h[1];
        s2 += (float)p.h[2]; s3 += (float)p.h[3];
    }
    #pragma unroll 4
    for (int c = 0; c < 4 * t; ++c) {           // fb chunks: scale 2^E[j]
        float sc = pow2f(E_TAB[c >> 2]);
        F16x4v p;
        p.q = *(const uint2*)(pFB + (size_t)c * (CH_BYTES / 2) + eo);
        s0 += (float)p.h[0] * sc; s1 += (float)p.h[1] * sc;
        s2 += (float)p.h[2] * sc; s3 += (float)p.h[3] * sc;
    }
    float* ob = out + eo * P_ + t;
    ob[0 * P_] = s0; ob[1 * P_] = s1; ob[2 * P_] = s2; ob[3 * P_] = s3;
    if (t < 11) {                               // store y_{t+1} scaled by 2^-e
        float ds = pow2f(-E_TAB[t]);
        F16x4v o;
        o.h[0] = (_Float16)(s0 * ds); o.h[1] = (_Float16)(s1 * ds);
        o.h[2] = (_Float16)(s2 * ds); o.h[3] = (_Float16)(s3 * ds);
        *(uint2*)(H + h_off(12 + t, b, n0)) = o.q;   // 8B contiguous
    }
}

// ---------------- insurance: naive fp32 path if workspace is too small ----------------
__global__ void naive_step(const float* __restrict__ x, const float* __restrict__ W,
                           float* __restrict__ out, int t)
{
    int tid = blockIdx.x * 256 + threadIdx.x;   // 262144 threads: (b, j)
    int b = tid >> 11;
    int j = tid & (N_ - 1);
    float acc = 0.f;
    for (int i = 0; i < 12; ++i) {
        int g = t + i;
        const float* src = (g < 12) ? (x   + (size_t)b * (N_ * 12) + g)
                                    : (out + (size_t)b * (N_ * 12) + (g - 12));
        const float* wr = W + ((size_t)i * N_ + j) * N_;
        for (int k = 0; k < N_; ++k)
            acc += wr[k] * src[(size_t)k * 12];
    }
    out[((size_t)b * N_ + j) * 12 + t] = acc;
}

extern "C" void kernel_launch(void* const* d_in, const int* in_sizes, int n_in,
                              void* d_out, int out_size, void* d_ws, size_t ws_size,
                              hipStream_t stream)
{
    const float* x = (const float*)d_in[0];
    const float* W = (const float*)d_in[1];
    float* out = (float*)d_out;

    if (ws_size < WS_NEEDED) {                  // fallback: correct but slow
        for (int t = 0; t < 12; ++t)
            naive_step<<<1024, 256, 0, stream>>>(x, W, out, t);
        return;
    }

    char* Wp = (char*)d_ws;
    char* H  = Wp + WPK_BYTES;
    _Float16* pF  = (_Float16*)(H + H_BYTES);
    _Float16* pFB = (_Float16*)(H + H_BYTES + PF_BYTES);

    prep_all<<<6272, 256, 0, stream>>>(x, W, Wp, H);
    gemm_F<<<1248, 256, 0, stream>>>(Wp, H, pF);
    reduce_step<<<256, 256, 0, stream>>>(pF, pFB, out, H, 0);
    for (int t = 1; t < 12; ++t) {
        gemm_FB<<<64 * t, 256, 0, stream>>>(Wp, H, pFB, t);
        reduce_step<<<256, 256, 0, stream>>>(pF, pFB, out, H, t);
    }
}

// Round 12
// 492.373 us; speedup vs baseline: 1.0963x; 1.0030x over previous
//
#include <hip/hip_runtime.h>
#include <stdint.h>

// AR(12) rollout, feed-forward/feedback decomposition.
// y_{t+1} = F_{t+1} + sum_{j=0..t-1} W_{12-t+j} . y_{j+1}
// R11 = R10 with ONE change: gemm_F's bid->(j,slot,nt) mapping re-bucketed so
// the (12-j) blocks sharing a (j,nt) W-slice land on the SAME XCD within ~96
// consecutive bids -> W read from L3 once (100 MB), re-reads hit L2. R10's
// t-major scatter put ~22 MB concurrent W per XCD (>> 4MB L2) -> 639 MB L3
// stream -> the measured 143 us / MfmaUtil 24%.

typedef _Float16 f16x8 __attribute__((ext_vector_type(8)));
typedef float    f32x4 __attribute__((ext_vector_type(4)));

#define B_ 128
#define N_ 2048
#define P_ 12
#define K_ (P_*N_)          // 24576
#define NT 16               // N-tiles of 128
#define NKP (K_/64)         // 384 BK64 W-tiles per nt column

#define WPK_BYTES    ((size_t)NT*NKP*16384)    // 100,663,296 (fp16, tiled)
#define H_SLOT_BYTES ((size_t)B_*N_*2)         // 524,288 per window slot
#define H_BYTES      (23*H_SLOT_BYTES)         // 12,058,624
#define CH_BYTES     ((size_t)B_*N_*2)         // one partial chunk (fp16)
#define PF_BYTES     (78*CH_BYTES)             // 40,894,464
#define PFB_BYTES    (44*CH_BYTES)             // 23,068,672
#define WS_NEEDED    (WPK_BYTES + H_BYTES + PF_BYTES + PFB_BYTES)  // ~177 MB

// Scale exponents for y_{t+1} (t=0..10): e = round(7.29 + 5.50*t) from the
// variance recursion sigma(y_1)=sqrt(24576), growth sqrt(2048) per step.
__device__ __constant__ int E_TAB[11] = {7, 13, 18, 24, 29, 35, 40, 46, 51, 57, 62};

__device__ __forceinline__ float pow2f(int e) {      // exact 2^e, |e| < 127
    return __uint_as_float((uint32_t)(127 + e) << 23);
}

union F16x8 { _Float16 h[8]; uint4 q; };
union F16x4v { _Float16 h[4]; uint2 q; };

// ---- H (window) layout: [slot][kblk=k/32][ko=(k%32)/8][b][8 elems] fp16 ----
__device__ __forceinline__ uint32_t h_off(int slot, int b, int k) {
    return (uint32_t)slot * (uint32_t)H_SLOT_BYTES
         + (uint32_t)(k >> 5) * 8192u + (uint32_t)(((k >> 3) & 3) << 11)
         + (uint32_t)(b << 4) + (uint32_t)((k & 7) << 1);
}
// ---- Wp (B) layout: tile(nt, pk) = 16 KB covering BK=64 x BN=128 (proven) ----
__device__ __forceinline__ size_t w_tile_base(int nt, int pk) {
    return ((size_t)nt * NKP + (size_t)pk) * 16384;
}

// ---------------- prep: x->H (blocks 0..127), W->Wp (128..6271) ----------------
__global__ void prep_all(const float* __restrict__ x, const float* __restrict__ W,
                         char* __restrict__ Wp, char* __restrict__ H)
{
    __shared__ float tile[128][68];   // +4 pad
    int bid = blockIdx.x, t = threadIdx.x;
    if (bid < 128) {
        int tg = bid * 256 + t;                 // 32768 threads: (b, n-octet)
        int b = tg >> 8;
        int n0 = (tg & 255) << 3;
        const float4* s4 = (const float4*)(x + ((size_t)b * N_ + n0) * P_);
        float4 tmp[24];
        #pragma unroll
        for (int i2 = 0; i2 < 24; ++i2) tmp[i2] = s4[i2];
        #pragma unroll
        for (int p = 0; p < 12; ++p) {
            F16x8 o;
            #pragma unroll
            for (int q = 0; q < 8; ++q) {
                int fi = q * 12 + p;            // compile-time constant
                float4 blk = tmp[fi >> 2];
                float f = ((fi & 3) == 0) ? blk.x : ((fi & 3) == 1) ? blk.y : ((fi & 3) == 2) ? blk.z : blk.w;
                o.h[q] = (_Float16)f;
            }
            *(uint4*)(H + h_off(p, b, n0)) = o.q;
        }
        return;
    }
    int u = bid - 128;                          // 0..6143 = 16 nt x 384 pk
    int nt = u / NKP, pk = u % NKP;
    int i  = pk >> 5;                           // W slice 0..11
    int k0 = (pk & 31) << 6;                    // k-in-slice
    int j0 = nt << 7;
    #pragma unroll
    for (int pass = 0; pass < 8; ++pass) {      // coalesced fp32 reads along k
        int jl = pass * 16 + (t >> 4);
        int kq = (t & 15) * 4;
        float4 v = *(const float4*)(W + ((size_t)i * N_ + (j0 + jl)) * N_ + k0 + kq);
        tile[jl][kq + 0] = v.x; tile[jl][kq + 1] = v.y;
        tile[jl][kq + 2] = v.z; tile[jl][kq + 3] = v.w;
    }
    __syncthreads();
    int ksub = t >> 7, c = t & 127;
    char* base = Wp + w_tile_base(nt, pk) + (ksub << 13);
    #pragma unroll
    for (int ko = 0; ko < 4; ++ko) {
        F16x8 o;
        #pragma unroll
        for (int q = 0; q < 8; ++q) o.h[q] = (_Float16)tile[c][ksub * 32 + ko * 8 + q];
        uint32_t off = (uint32_t)((c << 6) + (ko << 4)) ^ (uint32_t)((c & 7) << 4);
        *(uint4*)(base + off) = o.q;
    }
}

// ---------------- shared GEMM body: one K-chunk of one slot-product ----------------
__device__ __forceinline__ void gemm_body(
        const char* __restrict__ Wp, const char* __restrict__ H,
        _Float16* __restrict__ part, char* ldsB,
        int nt, int pk0, int slot, int k0, int nph)
{
    const int tid  = threadIdx.x;
    const int lane = tid & 63;
    const int wv   = tid >> 6;
    const int wr   = wv >> 1;                   // M half
    const int wc   = wv & 1;                    // N half
    const int l15  = lane & 15;
    const int ko   = lane >> 4;                 // k-octet 0..3
    const int jbase = (nt << 7) + (wc << 6) + l15;

    uint32_t boff[4];
    #pragma unroll
    for (int nf = 0; nf < 4; ++nf) {
        int c = (wc << 6) + (nf << 4) + l15;
        boff[nf] = (uint32_t)((c << 6) + (ko << 4)) ^ (uint32_t)((c & 7) << 4);
    }

    auto stage = [&](int buf, int ph) {         // 16 KB linear global->LDS
        const char* src = Wp + w_tile_base(nt, pk0 + ph);
        #pragma unroll
        for (int j = 0; j < 4; ++j) {
            uint32_t o = (uint32_t)(j << 12) + (uint32_t)(tid << 4);
            __builtin_amdgcn_global_load_lds(
                (const __attribute__((address_space(1))) void*)(src + o),
                (__attribute__((address_space(3))) void*)(ldsB + buf * 16384 + (j << 12) + (wv << 10)), 16, 0, 0);
        }
    };
    auto loadA = [&](int ph, f16x8 a[2][4]) {   // per-lane, coalesced 256B runs
        #pragma unroll
        for (int ksub = 0; ksub < 2; ++ksub) {
            int k = k0 + (ph << 6) + (ksub << 5);
            const char* sb = H + (size_t)slot * H_SLOT_BYTES
                           + (uint32_t)((k >> 5) << 13) + (uint32_t)(ko << 11);
            #pragma unroll
            for (int m = 0; m < 4; ++m) {
                int brow = (wr << 6) + (m << 4) + l15;
                a[ksub][m] = *(const f16x8*)(sb + (brow << 4));
            }
        }
    };

    f32x4 acc[4][4];
    #pragma unroll
    for (int m = 0; m < 4; ++m)
        #pragma unroll
        for (int n = 0; n < 4; ++n) acc[m][n] = (f32x4){0.f, 0.f, 0.f, 0.f};

    f16x8 a[2][4];
    loadA(0, a);
    stage(0, 0);
    __syncthreads();

    #pragma unroll 1
    for (int ph = 0; ph < nph; ++ph) {
        if (ph + 1 < nph) stage((ph & 1) ^ 1, ph + 1);
        const char* lb = ldsB + (ph & 1) * 16384;
        f16x8 bf[2][4];
        #pragma unroll
        for (int ksub = 0; ksub < 2; ++ksub)
            #pragma unroll
            for (int nf = 0; nf < 4; ++nf)
                bf[ksub][nf] = *(const f16x8*)(lb + (ksub << 13) + boff[nf]);
        f16x8 an[2][4];
        if (ph + 1 < nph) loadA(ph + 1, an);
        #pragma unroll
        for (int ksub = 0; ksub < 2; ++ksub)
            #pragma unroll
            for (int m = 0; m < 4; ++m)
                #pragma unroll
                for (int nf = 0; nf < 4; ++nf)
                    acc[m][nf] = __builtin_amdgcn_mfma_f32_16x16x32_f16(a[ksub][m], bf[ksub][nf], acc[m][nf], 0, 0, 0);
        #pragma unroll
        for (int ksub = 0; ksub < 2; ++ksub)
            #pragma unroll
            for (int m = 0; m < 4; ++m) a[ksub][m] = an[ksub][m];
        __syncthreads();
    }

    // C/D layout (verified R0-R10): col = lane&15, row = (lane>>4)*4 + reg
    const int r0 = (lane >> 4) << 2;
    _Float16* pb = part + ((size_t)((wr << 6) + r0)) * N_ + jbase;
    #pragma unroll
    for (int m = 0; m < 4; ++m)
        #pragma unroll
        for (int n = 0; n < 4; ++n)
            #pragma unroll
            for (int r = 0; r < 4; ++r)
                pb[(size_t)(m * 16 + r) * N_ + n * 16] = (_Float16)acc[m][n][r];
}

// ---------------- F: all 78 x-slot products, one launch, XCD-bucketed ----------------
// bid = bucket*96 + m*8 + gx; group g = bucket*8+gx -> (j = g>>4, nt = g&15);
// member m -> slot s = j+m (skip if s>11). All members of a group: same bid%8
// (same XCD) and within 96 consecutive bids -> W-slice (512 KB) read from L3
// once, 11 re-reads hit L2 (~2.5 MB concurrent W per XCD < 4 MB).
__global__ __launch_bounds__(256, 2) void gemm_F(
        const char* __restrict__ Wp, const char* __restrict__ H,
        _Float16* __restrict__ pF)
{
    __shared__ alignas(16) char ldsB[2 * 16384];
    int bid = blockIdx.x;
    int bucket = bid / 96;
    int w = bid % 96;
    int m  = w >> 3;                            // member 0..11
    int g  = bucket * 8 + (w & 7);              // group 0..191
    int j  = g >> 4;                            // W slice 0..11
    int nt = g & 15;
    int s  = j + m;                             // window slot
    if (s > 11) return;                         // padded member
    int t = m;                                  // = s - j, step offset
    int idx = t * 12 - t * (t - 1) / 2 + j;     // t-major storage for reduce
    gemm_body(Wp, H, pF + (size_t)idx * (CH_BYTES / 2), ldsB,
              nt, j * 32, s, 0, 32);
}

// ---------------- feedback step t: K = t*2048 over y-slots, 4t chunks ----------------
// grid 64t = 4t chunks x 16 nt. Chunk c: j=c>>2 (y-slot 12+j), sub=c&3.
__global__ __launch_bounds__(256, 2) void gemm_FB(
        const char* __restrict__ Wp, const char* __restrict__ H,
        _Float16* __restrict__ pFB, int t)
{
    __shared__ alignas(16) char ldsB[2 * 16384];
    int c = blockIdx.x >> 4, nt = blockIdx.x & 15;
    int j = c >> 2, sub = c & 3;
    int i = 12 - t + j;                         // W slice index in window
    gemm_body(Wp, H, pFB + (size_t)c * (CH_BYTES / 2), ldsB,
              nt, i * 32 + sub * 8, 12 + j, sub * 512, 8);
}

// ---------------- reduce step t: y_{t+1} = sum F-chunks + scaled fb-chunks ----------------
__global__ void reduce_step(const _Float16* __restrict__ pF, const _Float16* __restrict__ pFB,
                            float* __restrict__ out, char* __restrict__ H, int t)
{
    int tid = blockIdx.x * 256 + threadIdx.x;   // 65536 threads: (b, n-quad)
    int b = tid >> 9;
    int n0 = (tid & 511) << 2;
    const size_t eo = (size_t)b * N_ + n0;
    float s0 = 0.f, s1 = 0.f, s2 = 0.f, s3 = 0.f;
    int baseT = t * 12 - t * (t - 1) / 2;
    int nF = 12 - t;
    #pragma unroll 4
    for (int f = 0; f < nF; ++f) {              // F chunks: scale 1 (x domain)
        F16x4v p;
        p.q = *(const uint2*)(pF + (size_t)(baseT + f) * (CH_BYTES / 2) + eo);
        s0 += (float)p.h[0]; s1 += (float)p.h[1];
        s2 += (float)p.h[2]; s3 += (float)p.h[3];
    }
    #pragma unroll 4
    for (int c = 0; c < 4 * t; ++c) {           // fb chunks: scale 2^E[j]
        float sc = pow2f(E_TAB[c >> 2]);
        F16x4v p;
        p.q = *(const uint2*)(pFB + (size_t)c * (CH_BYTES / 2) + eo);
        s0 += (float)p.h[0] * sc; s1 += (float)p.h[1] * sc;
        s2 += (float)p.h[2] * sc; s3 += (float)p.h[3] * sc;
    }
    float* ob = out + eo * P_ + t;
    ob[0 * P_] = s0; ob[1 * P_] = s1; ob[2 * P_] = s2; ob[3 * P_] = s3;
    if (t < 11) {                               // store y_{t+1} scaled by 2^-e
        float ds = pow2f(-E_TAB[t]);
        F16x4v o;
        o.h[0] = (_Float16)(s0 * ds); o.h[1] = (_Float16)(s1 * ds);
        o.h[2] = (_Float16)(s2 * ds); o.h[3] = (_Float16)(s3 * ds);
        *(uint2*)(H + h_off(12 + t, b, n0)) = o.q;   // 8B contiguous
    }
}

// ---------------- insurance: naive fp32 path if workspace is too small ----------------
__global__ void naive_step(const float* __restrict__ x, const float* __restrict__ W,
                           float* __restrict__ out, int t)
{
    int tid = blockIdx.x * 256 + threadIdx.x;   // 262144 threads: (b, j)
    int b = tid >> 11;
    int j = tid & (N_ - 1);
    float acc = 0.f;
    for (int i = 0; i < 12; ++i) {
        int g = t + i;
        const float* src = (g < 12) ? (x   + (size_t)b * (N_ * 12) + g)
                                    : (out + (size_t)b * (N_ * 12) + (g - 12));
        const float* wr = W + ((size_t)i * N_ + j) * N_;
        for (int k = 0; k < N_; ++k)
            acc += wr[k] * src[(size_t)k * 12];
    }
    out[((size_t)b * N_ + j) * 12 + t] = acc;
}

extern "C" void kernel_launch(void* const* d_in, const int* in_sizes, int n_in,
                              void* d_out, int out_size, void* d_ws, size_t ws_size,
                              hipStream_t stream)
{
    const float* x = (const float*)d_in[0];
    const float* W = (const float*)d_in[1];
    float* out = (float*)d_out;

    if (ws_size < WS_NEEDED) {                  // fallback: correct but slow
        for (int t = 0; t < 12; ++t)
            naive_step<<<1024, 256, 0, stream>>>(x, W, out, t);
        return;
    }

    char* Wp = (char*)d_ws;
    char* H  = Wp + WPK_BYTES;
    _Float16* pF  = (_Float16*)(H + H_BYTES);
    _Float16* pFB = (_Float16*)(H + H_BYTES + PF_BYTES);

    prep_all<<<6272, 256, 0, stream>>>(x, W, Wp, H);
    gemm_F<<<2304, 256, 0, stream>>>(Wp, H, pF);
    reduce_step<<<256, 256, 0, stream>>>(pF, pFB, out, H, 0);
    for (int t = 1; t < 12; ++t) {
        gemm_FB<<<64 * t, 256, 0, stream>>>(Wp, H, pFB, t);
        reduce_step<<<256, 256, 0, stream>>>(pF, pFB, out, H, t);
    }
}

// Round 13
// 458.308 us; speedup vs baseline: 1.1778x; 1.0743x over previous
//
#include <hip/hip_runtime.h>
#include <stdint.h>

// AR(12) rollout, feed-forward/feedback decomposition.
// y_{t+1} = F_{t+1} + sum_{j=0..t-1} W_{12-t+j} . y_{j+1}
// R12: gemm body rebuilt to the m97-proven structure: BOTH operands staged via
// global_load_lds (A back to the R1-R4 XOR-swizzled H layout), BK=32, 32 KB
// LDS -> 4-5 blocks/CU so co-resident blocks' MFMA fills each block's barrier
// drain (m114 overlap). R11's per-lane A-loads put L2 latency in every phase's
// critical path at 2 blocks/CU -> measured 591 TF / MfmaUtil 24%.

typedef _Float16 f16x8 __attribute__((ext_vector_type(8)));
typedef float    f32x4 __attribute__((ext_vector_type(4)));

#define B_ 128
#define N_ 2048
#define P_ 12
#define K_ (P_*N_)          // 24576
#define NT 16               // N-tiles of 128
#define NKP (K_/64)         // 384 BK64 W-tiles per nt column

#define WPK_BYTES    ((size_t)NT*NKP*16384)    // 100,663,296 (fp16, tiled)
#define H_SLOT_BYTES ((size_t)B_*N_*2)         // 524,288 per window slot
#define H_BYTES      (23*H_SLOT_BYTES)         // 12,058,624
#define CH_BYTES     ((size_t)B_*N_*2)         // one partial chunk (fp16)
#define PF_BYTES     (78*CH_BYTES)             // 40,894,464
#define PFB_BYTES    (44*CH_BYTES)             // 23,068,672
#define WS_NEEDED    (WPK_BYTES + H_BYTES + PF_BYTES + PFB_BYTES)  // ~177 MB

// Scale exponents for y_{t+1} (t=0..10): e = round(7.29 + 5.50*t) from the
// variance recursion sigma(y_1)=sqrt(24576), growth sqrt(2048) per step.
__device__ __constant__ int E_TAB[11] = {7, 13, 18, 24, 29, 35, 40, 46, 51, 57, 62};

__device__ __forceinline__ float pow2f(int e) {      // exact 2^e, |e| < 127
    return __uint_as_float((uint32_t)(127 + e) << 23);
}

union F16x8 { _Float16 h[8]; uint4 q; };
union F16x4v { _Float16 h[4]; uint2 q; };

// ---- H (window) layout (R1-R4 proven): [slot][kblk=k/32][b][k%32] fp16 with
// XOR swizzle per 8KB tile: byte = (b*64 + (k&31)*2) ^ ((b&7)<<4).
// Linear global_load_lds staging + conflict-free ds_read_b128 fragments.
__device__ __forceinline__ uint32_t h_off(int slot, int b, int k) {
    uint32_t t = (uint32_t)((b << 6) + ((k & 31) << 1)) ^ (uint32_t)((b & 7) << 4);
    return (uint32_t)slot * (uint32_t)H_SLOT_BYTES + (uint32_t)(k >> 5) * 8192u + t;
}
// ---- Wp (B) layout: tile(nt, pk) = 16 KB covering BK=64 x BN=128 (proven) ----
__device__ __forceinline__ size_t w_tile_base(int nt, int pk) {
    return ((size_t)nt * NKP + (size_t)pk) * 16384;
}

// ---------------- prep: x->H (blocks 0..127), W->Wp (128..6271) ----------------
__global__ void prep_all(const float* __restrict__ x, const float* __restrict__ W,
                         char* __restrict__ Wp, char* __restrict__ H)
{
    __shared__ float tile[128][68];   // +4 pad
    int bid = blockIdx.x, t = threadIdx.x;
    if (bid < 128) {
        int tg = bid * 256 + t;                 // 32768 threads: (b, n-octet)
        int b = tg >> 8;
        int n0 = (tg & 255) << 3;
        const float4* s4 = (const float4*)(x + ((size_t)b * N_ + n0) * P_);
        float4 tmp[24];
        #pragma unroll
        for (int i2 = 0; i2 < 24; ++i2) tmp[i2] = s4[i2];
        #pragma unroll
        for (int p = 0; p < 12; ++p) {
            F16x8 o;
            #pragma unroll
            for (int q = 0; q < 8; ++q) {
                int fi = q * 12 + p;            // compile-time constant
                float4 blk = tmp[fi >> 2];
                float f = ((fi & 3) == 0) ? blk.x : ((fi & 3) == 1) ? blk.y : ((fi & 3) == 2) ? blk.z : blk.w;
                o.h[q] = (_Float16)f;
            }
            *(uint4*)(H + h_off(p, b, n0)) = o.q;   // 16B-aligned under swizzle
        }
        return;
    }
    int u = bid - 128;                          // 0..6143 = 16 nt x 384 pk
    int nt = u / NKP, pk = u % NKP;
    int i  = pk >> 5;                           // W slice 0..11
    int k0 = (pk & 31) << 6;                    // k-in-slice
    int j0 = nt << 7;
    #pragma unroll
    for (int pass = 0; pass < 8; ++pass) {      // coalesced fp32 reads along k
        int jl = pass * 16 + (t >> 4);
        int kq = (t & 15) * 4;
        float4 v = *(const float4*)(W + ((size_t)i * N_ + (j0 + jl)) * N_ + k0 + kq);
        tile[jl][kq + 0] = v.x; tile[jl][kq + 1] = v.y;
        tile[jl][kq + 2] = v.z; tile[jl][kq + 3] = v.w;
    }
    __syncthreads();
    int ksub = t >> 7, c = t & 127;
    char* base = Wp + w_tile_base(nt, pk) + (ksub << 13);
    #pragma unroll
    for (int ko = 0; ko < 4; ++ko) {
        F16x8 o;
        #pragma unroll
        for (int q = 0; q < 8; ++q) o.h[q] = (_Float16)tile[c][ksub * 32 + ko * 8 + q];
        uint32_t off = (uint32_t)((c << 6) + (ko << 4)) ^ (uint32_t)((c & 7) << 4);
        *(uint4*)(base + off) = o.q;
    }
}

// ---------------- shared GEMM body (m97 structure): one K-chunk ----------------
// Both A (from swizzled H slot) and B (from Wp tiles) staged 8KB each per
// BK=32 phase via global_load_lds; 2-buffer, 1 barrier per phase; 32 KB LDS.
__device__ __forceinline__ void gemm_body(
        const char* __restrict__ Wp, const char* __restrict__ H,
        _Float16* __restrict__ part, char* ldsAB,
        int nt, int pk0, int slot, int k0, int nph)
{
    const int tid  = threadIdx.x;
    const int lane = tid & 63;
    const int wv   = tid >> 6;
    const int wr   = wv >> 1;                   // M half
    const int wc   = wv & 1;                    // N half
    const int l15  = lane & 15;
    const int ko   = lane >> 4;                 // k-octet 0..3
    const int jbase = (nt << 7) + (wc << 6) + l15;

    // A/B fragment byte offsets inside an 8KB half (R1-R4 proven swizzle)
    uint32_t aoff[4], boff[4];
    #pragma unroll
    for (int m = 0; m < 4; ++m) {
        int row = (wr << 6) + (m << 4) + l15;
        aoff[m] = (uint32_t)((row << 6) + (ko << 4)) ^ (uint32_t)((row & 7) << 4);
    }
    #pragma unroll
    for (int nf = 0; nf < 4; ++nf) {
        int c = (wc << 6) + (nf << 4) + l15;
        boff[nf] = (uint32_t)((c << 6) + (ko << 4)) ^ (uint32_t)((c & 7) << 4);
    }

    // LDS map: ldsAB[buf*16384 + which*8192 + off], which: 0=A, 1=B
    auto stage = [&](int buf, int ph) {         // A 8KB + B 8KB, linear
        int k = k0 + (ph << 5);
        const char* sA = H + (size_t)slot * H_SLOT_BYTES + (uint32_t)((k >> 5) << 13);
        const char* sB = Wp + w_tile_base(nt, pk0 + (ph >> 1)) + (uint32_t)((ph & 1) << 13);
        #pragma unroll
        for (int j = 0; j < 2; ++j) {
            uint32_t o = (uint32_t)(j << 12) + (uint32_t)(tid << 4);
            uint32_t d = (uint32_t)(j << 12) + (uint32_t)(wv << 10);
            __builtin_amdgcn_global_load_lds(
                (const __attribute__((address_space(1))) void*)(sA + o),
                (__attribute__((address_space(3))) void*)(ldsAB + buf * 16384 + d), 16, 0, 0);
            __builtin_amdgcn_global_load_lds(
                (const __attribute__((address_space(1))) void*)(sB + o),
                (__attribute__((address_space(3))) void*)(ldsAB + buf * 16384 + 8192 + d), 16, 0, 0);
        }
    };

    f32x4 acc[4][4];
    #pragma unroll
    for (int m = 0; m < 4; ++m)
        #pragma unroll
        for (int n = 0; n < 4; ++n) acc[m][n] = (f32x4){0.f, 0.f, 0.f, 0.f};

    stage(0, 0);
    __syncthreads();                            // compiler drains vmcnt

    #pragma unroll 1
    for (int ph = 0; ph < nph; ++ph) {
        if (ph + 1 < nph) stage((ph & 1) ^ 1, ph + 1);   // prefetch other buffer
        const char* lA = ldsAB + (ph & 1) * 16384;
        const char* lB = lA + 8192;
        f16x8 ah[4], bf[4];
        #pragma unroll
        for (int m = 0; m < 4; ++m) ah[m] = *(const f16x8*)(lA + aoff[m]);
        #pragma unroll
        for (int nf = 0; nf < 4; ++nf) bf[nf] = *(const f16x8*)(lB + boff[nf]);
        #pragma unroll
        for (int m = 0; m < 4; ++m)
            #pragma unroll
            for (int nf = 0; nf < 4; ++nf)
                acc[m][nf] = __builtin_amdgcn_mfma_f32_16x16x32_f16(ah[m], bf[nf], acc[m][nf], 0, 0, 0);
        __syncthreads();                        // reads done before next overwrite
    }

    // C/D layout (verified R0-R11): col = lane&15, row = (lane>>4)*4 + reg
    const int r0 = (lane >> 4) << 2;
    _Float16* pb = part + ((size_t)((wr << 6) + r0)) * N_ + jbase;
    #pragma unroll
    for (int m = 0; m < 4; ++m)
        #pragma unroll
        for (int n = 0; n < 4; ++n)
            #pragma unroll
            for (int r = 0; r < 4; ++r)
                pb[(size_t)(m * 16 + r) * N_ + n * 16] = (_Float16)acc[m][n][r];
}

// ---------------- F: all 78 x-slot products, one launch, XCD-bucketed ----------------
__global__ __launch_bounds__(256, 4) void gemm_F(
        const char* __restrict__ Wp, const char* __restrict__ H,
        _Float16* __restrict__ pF)
{
    __shared__ alignas(16) char ldsAB[2 * 16384];
    int bid = blockIdx.x;
    int bucket = bid / 96;
    int w = bid % 96;
    int m  = w >> 3;                            // member 0..11
    int g  = bucket * 8 + (w & 7);              // group 0..191
    int j  = g >> 4;                            // W slice 0..11
    int nt = g & 15;
    int s  = j + m;                             // window slot
    if (s > 11) return;                         // padded member
    int t = m;                                  // = s - j, step offset
    int idx = t * 12 - t * (t - 1) / 2 + j;     // t-major storage for reduce
    gemm_body(Wp, H, pF + (size_t)idx * (CH_BYTES / 2), ldsAB,
              nt, j * 32, s, 0, 64);
}

// ---------------- feedback step t: K = t*2048 over y-slots, 4t chunks ----------------
__global__ __launch_bounds__(256, 4) void gemm_FB(
        const char* __restrict__ Wp, const char* __restrict__ H,
        _Float16* __restrict__ pFB, int t)
{
    __shared__ alignas(16) char ldsAB[2 * 16384];
    int c = blockIdx.x >> 4, nt = blockIdx.x & 15;
    int j = c >> 2, sub = c & 3;
    int i = 12 - t + j;                         // W slice index in window
    gemm_body(Wp, H, pFB + (size_t)c * (CH_BYTES / 2), ldsAB,
              nt, i * 32 + sub * 8, 12 + j, sub * 512, 16);
}

// ---------------- reduce step t: y_{t+1} = sum F-chunks + scaled fb-chunks ----------------
__global__ void reduce_step(const _Float16* __restrict__ pF, const _Float16* __restrict__ pFB,
                            float* __restrict__ out, char* __restrict__ H, int t)
{
    int tid = blockIdx.x * 256 + threadIdx.x;   // 65536 threads: (b, n-quad)
    int b = tid >> 9;
    int n0 = (tid & 511) << 2;
    const size_t eo = (size_t)b * N_ + n0;
    float s0 = 0.f, s1 = 0.f, s2 = 0.f, s3 = 0.f;
    int baseT = t * 12 - t * (t - 1) / 2;
    int nF = 12 - t;
    #pragma unroll 4
    for (int f = 0; f < nF; ++f) {              // F chunks: scale 1 (x domain)
        F16x4v p;
        p.q = *(const uint2*)(pF + (size_t)(baseT + f) * (CH_BYTES / 2) + eo);
        s0 += (float)p.h[0]; s1 += (float)p.h[1];
        s2 += (float)p.h[2]; s3 += (float)p.h[3];
    }
    #pragma unroll 4
    for (int c = 0; c < 4 * t; ++c) {           // fb chunks: scale 2^E[j]
        float sc = pow2f(E_TAB[c >> 2]);
        F16x4v p;
        p.q = *(const uint2*)(pFB + (size_t)c * (CH_BYTES / 2) + eo);
        s0 += (float)p.h[0] * sc; s1 += (float)p.h[1] * sc;
        s2 += (float)p.h[2] * sc; s3 += (float)p.h[3] * sc;
    }
    float* ob = out + eo * P_ + t;
    ob[0 * P_] = s0; ob[1 * P_] = s1; ob[2 * P_] = s2; ob[3 * P_] = s3;
    if (t < 11) {                               // store y_{t+1} scaled by 2^-e
        float ds = pow2f(-E_TAB[t]);
        F16x4v o;
        o.h[0] = (_Float16)(s0 * ds); o.h[1] = (_Float16)(s1 * ds);
        o.h[2] = (_Float16)(s2 * ds); o.h[3] = (_Float16)(s3 * ds);
        *(uint2*)(H + h_off(12 + t, b, n0)) = o.q;   // 8B-aligned under swizzle
    }
}

// ---------------- insurance: naive fp32 path if workspace is too small ----------------
__global__ void naive_step(const float* __restrict__ x, const float* __restrict__ W,
                           float* __restrict__ out, int t)
{
    int tid = blockIdx.x * 256 + threadIdx.x;   // 262144 threads: (b, j)
    int b = tid >> 11;
    int j = tid & (N_ - 1);
    float acc = 0.f;
    for (int i = 0; i < 12; ++i) {
        int g = t + i;
        const float* src = (g < 12) ? (x   + (size_t)b * (N_ * 12) + g)
                                    : (out + (size_t)b * (N_ * 12) + (g - 12));
        const float* wr = W + ((size_t)i * N_ + j) * N_;
        for (int k = 0; k < N_; ++k)
            acc += wr[k] * src[(size_t)k * 12];
    }
    out[((size_t)b * N_ + j) * 12 + t] = acc;
}

extern "C" void kernel_launch(void* const* d_in, const int* in_sizes, int n_in,
                              void* d_out, int out_size, void* d_ws, size_t ws_size,
                              hipStream_t stream)
{
    const float* x = (const float*)d_in[0];
    const float* W = (const float*)d_in[1];
    float* out = (float*)d_out;

    if (ws_size < WS_NEEDED) {                  // fallback: correct but slow
        for (int t = 0; t < 12; ++t)
            naive_step<<<1024, 256, 0, stream>>>(x, W, out, t);
        return;
    }

    char* Wp = (char*)d_ws;
    char* H  = Wp + WPK_BYTES;
    _Float16* pF  = (_Float16*)(H + H_BYTES);
    _Float16* pFB = (_Float16*)(H + H_BYTES + PF_BYTES);

    prep_all<<<6272, 256, 0, stream>>>(x, W, Wp, H);
    gemm_F<<<2304, 256, 0, stream>>>(Wp, H, pF);
    reduce_step<<<256, 256, 0, stream>>>(pF, pFB, out, H, 0);
    for (int t = 1; t < 12; ++t) {
        gemm_FB<<<64 * t, 256, 0, stream>>>(Wp, H, pFB, t);
        reduce_step<<<256, 256, 0, stream>>>(pF, pFB, out, H, t);
    }
}

// Round 14
// 444.405 us; speedup vs baseline: 1.2147x; 1.0313x over previous
//
#include <hip/hip_runtime.h>
#include <stdint.h>

// AR(12) rollout, feed-forward/feedback decomposition.
// y_{t+1} = F_{t+1} + sum_{j=0..t-1} W_{12-t+j} . y_{j+1}
// R13 = R12 + counted-vmcnt pipeline (T3/T4): 3 LDS buffers, stages issued 2
// phases ahead, per-phase wait vmcnt(4) (stage in flight stays in flight),
// raw s_barrier. Clean now: ALL loop VMEM = global_load_lds (R2's failed
// graft had per-lane register loads polluting the counts). 48KB LDS,
// 3 blocks/CU. fp16 single-product + exact pow2 slot scales (R4-R12).

typedef _Float16 f16x8 __attribute__((ext_vector_type(8)));
typedef float    f32x4 __attribute__((ext_vector_type(4)));

#define B_ 128
#define N_ 2048
#define P_ 12
#define K_ (P_*N_)          // 24576
#define NT 16               // N-tiles of 128
#define NKP (K_/64)         // 384 BK64 W-tiles per nt column

#define WPK_BYTES    ((size_t)NT*NKP*16384)    // 100,663,296 (fp16, tiled)
#define H_SLOT_BYTES ((size_t)B_*N_*2)         // 524,288 per window slot
#define H_BYTES      (23*H_SLOT_BYTES)         // 12,058,624
#define CH_BYTES     ((size_t)B_*N_*2)         // one partial chunk (fp16)
#define PF_BYTES     (78*CH_BYTES)             // 40,894,464
#define PFB_BYTES    (44*CH_BYTES)             // 23,068,672
#define WS_NEEDED    (WPK_BYTES + H_BYTES + PF_BYTES + PFB_BYTES)  // ~177 MB

// Scale exponents for y_{t+1} (t=0..10): e = round(7.29 + 5.50*t) from the
// variance recursion sigma(y_1)=sqrt(24576), growth sqrt(2048) per step.
__device__ __constant__ int E_TAB[11] = {7, 13, 18, 24, 29, 35, 40, 46, 51, 57, 62};

__device__ __forceinline__ float pow2f(int e) {      // exact 2^e, |e| < 127
    return __uint_as_float((uint32_t)(127 + e) << 23);
}

union F16x8 { _Float16 h[8]; uint4 q; };
union F16x4v { _Float16 h[4]; uint2 q; };

// ---- H (window) layout (R1-R4 proven): [slot][kblk=k/32][b][k%32] fp16 with
// XOR swizzle per 8KB tile: byte = (b*64 + (k&31)*2) ^ ((b&7)<<4).
__device__ __forceinline__ uint32_t h_off(int slot, int b, int k) {
    uint32_t t = (uint32_t)((b << 6) + ((k & 31) << 1)) ^ (uint32_t)((b & 7) << 4);
    return (uint32_t)slot * (uint32_t)H_SLOT_BYTES + (uint32_t)(k >> 5) * 8192u + t;
}
// ---- Wp (B) layout: tile(nt, pk) = 16 KB covering BK=64 x BN=128 (proven) ----
__device__ __forceinline__ size_t w_tile_base(int nt, int pk) {
    return ((size_t)nt * NKP + (size_t)pk) * 16384;
}

// ---------------- prep: x->H (blocks 0..127), W->Wp (128..6271) ----------------
__global__ void prep_all(const float* __restrict__ x, const float* __restrict__ W,
                         char* __restrict__ Wp, char* __restrict__ H)
{
    __shared__ float tile[128][68];   // +4 pad
    int bid = blockIdx.x, t = threadIdx.x;
    if (bid < 128) {
        int tg = bid * 256 + t;                 // 32768 threads: (b, n-octet)
        int b = tg >> 8;
        int n0 = (tg & 255) << 3;
        const float4* s4 = (const float4*)(x + ((size_t)b * N_ + n0) * P_);
        float4 tmp[24];
        #pragma unroll
        for (int i2 = 0; i2 < 24; ++i2) tmp[i2] = s4[i2];
        #pragma unroll
        for (int p = 0; p < 12; ++p) {
            F16x8 o;
            #pragma unroll
            for (int q = 0; q < 8; ++q) {
                int fi = q * 12 + p;            // compile-time constant
                float4 blk = tmp[fi >> 2];
                float f = ((fi & 3) == 0) ? blk.x : ((fi & 3) == 1) ? blk.y : ((fi & 3) == 2) ? blk.z : blk.w;
                o.h[q] = (_Float16)f;
            }
            *(uint4*)(H + h_off(p, b, n0)) = o.q;   // 16B-aligned under swizzle
        }
        return;
    }
    int u = bid - 128;                          // 0..6143 = 16 nt x 384 pk
    int nt = u / NKP, pk = u % NKP;
    int i  = pk >> 5;                           // W slice 0..11
    int k0 = (pk & 31) << 6;                    // k-in-slice
    int j0 = nt << 7;
    #pragma unroll
    for (int pass = 0; pass < 8; ++pass) {      // coalesced fp32 reads along k
        int jl = pass * 16 + (t >> 4);
        int kq = (t & 15) * 4;
        float4 v = *(const float4*)(W + ((size_t)i * N_ + (j0 + jl)) * N_ + k0 + kq);
        tile[jl][kq + 0] = v.x; tile[jl][kq + 1] = v.y;
        tile[jl][kq + 2] = v.z; tile[jl][kq + 3] = v.w;
    }
    __syncthreads();
    int ksub = t >> 7, c = t & 127;
    char* base = Wp + w_tile_base(nt, pk) + (ksub << 13);
    #pragma unroll
    for (int ko = 0; ko < 4; ++ko) {
        F16x8 o;
        #pragma unroll
        for (int q = 0; q < 8; ++q) o.h[q] = (_Float16)tile[c][ksub * 32 + ko * 8 + q];
        uint32_t off = (uint32_t)((c << 6) + (ko << 4)) ^ (uint32_t)((c & 7) << 4);
        *(uint4*)(base + off) = o.q;
    }
}

// ---------------- shared GEMM body: counted-vmcnt 3-buffer pipeline ----------------
// Per BK=32 phase: A 8KB (swizzled H) + B 8KB (Wp) staged via global_load_lds
// (4 insts/thread); stages run 2 phases ahead; wait vmcnt(4) per phase (tail:
// vmcnt(0)); raw s_barrier (NOT __syncthreads -> would drain vmcnt to 0).
__device__ __forceinline__ void gemm_body(
        const char* __restrict__ Wp, const char* __restrict__ H,
        _Float16* __restrict__ part, char* ldsAB,
        int nt, int pk0, int slot, int k0, int nph)
{
    const int tid  = threadIdx.x;
    const int lane = tid & 63;
    const int wv   = tid >> 6;
    const int wr   = wv >> 1;                   // M half
    const int wc   = wv & 1;                    // N half
    const int l15  = lane & 15;
    const int ko   = lane >> 4;                 // k-octet 0..3
    const int jbase = (nt << 7) + (wc << 6) + l15;

    // A/B fragment byte offsets inside an 8KB half (R1-R12 proven swizzle)
    uint32_t aoff[4], boff[4];
    #pragma unroll
    for (int m = 0; m < 4; ++m) {
        int row = (wr << 6) + (m << 4) + l15;
        aoff[m] = (uint32_t)((row << 6) + (ko << 4)) ^ (uint32_t)((row & 7) << 4);
    }
    #pragma unroll
    for (int nf = 0; nf < 4; ++nf) {
        int c = (wc << 6) + (nf << 4) + l15;
        boff[nf] = (uint32_t)((c << 6) + (ko << 4)) ^ (uint32_t)((c & 7) << 4);
    }

    // LDS map: ldsAB[buf*16384 + which*8192 + off], buf 0..2, which: 0=A 1=B
    auto stage = [&](int buf, int ph) {         // A 8KB + B 8KB, 4 insts/thread
        int k = k0 + (ph << 5);
        const char* sA = H + (size_t)slot * H_SLOT_BYTES + (uint32_t)((k >> 5) << 13);
        const char* sB = Wp + w_tile_base(nt, pk0 + (ph >> 1)) + (uint32_t)((ph & 1) << 13);
        #pragma unroll
        for (int j = 0; j < 2; ++j) {
            uint32_t o = (uint32_t)(j << 12) + (uint32_t)(tid << 4);
            uint32_t d = (uint32_t)(j << 12) + (uint32_t)(wv << 10);
            __builtin_amdgcn_global_load_lds(
                (const __attribute__((address_space(1))) void*)(sA + o),
                (__attribute__((address_space(3))) void*)(ldsAB + buf * 16384 + d), 16, 0, 0);
            __builtin_amdgcn_global_load_lds(
                (const __attribute__((address_space(1))) void*)(sB + o),
                (__attribute__((address_space(3))) void*)(ldsAB + buf * 16384 + 8192 + d), 16, 0, 0);
        }
    };

    f32x4 acc[4][4];
    #pragma unroll
    for (int m = 0; m < 4; ++m)
        #pragma unroll
        for (int n = 0; n < 4; ++n) acc[m][n] = (f32x4){0.f, 0.f, 0.f, 0.f};

    // prologue: 2 stages in flight; ensure stage(0) landed (4 left outstanding)
    stage(0, 0);
    stage(1, 1);
    asm volatile("s_waitcnt vmcnt(4) lgkmcnt(0)" ::: "memory");
    __builtin_amdgcn_s_barrier();

    int cur = 0;                                // buffer of phase ph
    #pragma unroll 1
    for (int ph = 0; ph < nph; ++ph) {
        int nxt2 = cur + 2; if (nxt2 >= 3) nxt2 -= 3;       // (ph+2)%3
        if (ph + 2 < nph) stage(nxt2, ph + 2);  // issue ahead; stays in flight
        const char* lA = ldsAB + cur * 16384;
        const char* lB = lA + 8192;
        f16x8 ah[4], bf[4];
        #pragma unroll
        for (int m = 0; m < 4; ++m) ah[m] = *(const f16x8*)(lA + aoff[m]);
        #pragma unroll
        for (int nf = 0; nf < 4; ++nf) bf[nf] = *(const f16x8*)(lB + boff[nf]);
        #pragma unroll
        for (int m = 0; m < 4; ++m)
            #pragma unroll
            for (int nf = 0; nf < 4; ++nf)
                acc[m][nf] = __builtin_amdgcn_mfma_f32_16x16x32_f16(ah[m], bf[nf], acc[m][nf], 0, 0, 0);
        if (ph + 1 < nph) {
            // need stage(ph+1) landed; stage(ph+2) (4 insts) may stay in flight
            if (ph + 2 < nph) asm volatile("s_waitcnt vmcnt(4) lgkmcnt(0)" ::: "memory");
            else              asm volatile("s_waitcnt vmcnt(0) lgkmcnt(0)" ::: "memory");
            __builtin_amdgcn_s_barrier();
        }
        ++cur; if (cur == 3) cur = 0;
    }

    // C/D layout (verified R0-R12): col = lane&15, row = (lane>>4)*4 + reg
    const int r0 = (lane >> 4) << 2;
    _Float16* pb = part + ((size_t)((wr << 6) + r0)) * N_ + jbase;
    #pragma unroll
    for (int m = 0; m < 4; ++m)
        #pragma unroll
        for (int n = 0; n < 4; ++n)
            #pragma unroll
            for (int r = 0; r < 4; ++r)
                pb[(size_t)(m * 16 + r) * N_ + n * 16] = (_Float16)acc[m][n][r];
}

// ---------------- F: all 78 x-slot products, one launch, XCD-bucketed ----------------
__global__ __launch_bounds__(256, 3) void gemm_F(
        const char* __restrict__ Wp, const char* __restrict__ H,
        _Float16* __restrict__ pF)
{
    __shared__ alignas(16) char ldsAB[3 * 16384];   // 48 KB -> 3 blocks/CU
    int bid = blockIdx.x;
    int bucket = bid / 96;
    int w = bid % 96;
    int m  = w >> 3;                            // member 0..11
    int g  = bucket * 8 + (w & 7);              // group 0..191
    int j  = g >> 4;                            // W slice 0..11
    int nt = g & 15;
    int s  = j + m;                             // window slot
    if (s > 11) return;                         // padded member
    int t = m;                                  // = s - j, step offset
    int idx = t * 12 - t * (t - 1) / 2 + j;     // t-major storage for reduce
    gemm_body(Wp, H, pF + (size_t)idx * (CH_BYTES / 2), ldsAB,
              nt, j * 32, s, 0, 64);
}

// ---------------- feedback step t: K = t*2048 over y-slots, 4t chunks ----------------
__global__ __launch_bounds__(256, 3) void gemm_FB(
        const char* __restrict__ Wp, const char* __restrict__ H,
        _Float16* __restrict__ pFB, int t)
{
    __shared__ alignas(16) char ldsAB[3 * 16384];
    int c = blockIdx.x >> 4, nt = blockIdx.x & 15;
    int j = c >> 2, sub = c & 3;
    int i = 12 - t + j;                         // W slice index in window
    gemm_body(Wp, H, pFB + (size_t)c * (CH_BYTES / 2), ldsAB,
              nt, i * 32 + sub * 8, 12 + j, sub * 512, 16);
}

// ---------------- reduce step t: y_{t+1} = sum F-chunks + scaled fb-chunks ----------------
__global__ void reduce_step(const _Float16* __restrict__ pF, const _Float16* __restrict__ pFB,
                            float* __restrict__ out, char* __restrict__ H, int t)
{
    int tid = blockIdx.x * 256 + threadIdx.x;   // 65536 threads: (b, n-quad)
    int b = tid >> 9;
    int n0 = (tid & 511) << 2;
    const size_t eo = (size_t)b * N_ + n0;
    float s0 = 0.f, s1 = 0.f, s2 = 0.f, s3 = 0.f;
    int baseT = t * 12 - t * (t - 1) / 2;
    int nF = 12 - t;
    #pragma unroll 4
    for (int f = 0; f < nF; ++f) {              // F chunks: scale 1 (x domain)
        F16x4v p;
        p.q = *(const uint2*)(pF + (size_t)(baseT + f) * (CH_BYTES / 2) + eo);
        s0 += (float)p.h[0]; s1 += (float)p.h[1];
        s2 += (float)p.h[2]; s3 += (float)p.h[3];
    }
    #pragma unroll 4
    for (int c = 0; c < 4 * t; ++c) {           // fb chunks: scale 2^E[j]
        float sc = pow2f(E_TAB[c >> 2]);
        F16x4v p;
        p.q = *(const uint2*)(pFB + (size_t)c * (CH_BYTES / 2) + eo);
        s0 += (float)p.h[0] * sc; s1 += (float)p.h[1] * sc;
        s2 += (float)p.h[2] * sc; s3 += (float)p.h[3] * sc;
    }
    float* ob = out + eo * P_ + t;
    ob[0 * P_] = s0; ob[1 * P_] = s1; ob[2 * P_] = s2; ob[3 * P_] = s3;
    if (t < 11) {                               // store y_{t+1} scaled by 2^-e
        float ds = pow2f(-E_TAB[t]);
        F16x4v o;
        o.h[0] = (_Float16)(s0 * ds); o.h[1] = (_Float16)(s1 * ds);
        o.h[2] = (_Float16)(s2 * ds); o.h[3] = (_Float16)(s3 * ds);
        *(uint2*)(H + h_off(12 + t, b, n0)) = o.q;   // 8B-aligned under swizzle
    }
}

// ---------------- insurance: naive fp32 path if workspace is too small ----------------
__global__ void naive_step(const float* __restrict__ x, const float* __restrict__ W,
                           float* __restrict__ out, int t)
{
    int tid = blockIdx.x * 256 + threadIdx.x;   // 262144 threads: (b, j)
    int b = tid >> 11;
    int j = tid & (N_ - 1);
    float acc = 0.f;
    for (int i = 0; i < 12; ++i) {
        int g = t + i;
        const float* src = (g < 12) ? (x   + (size_t)b * (N_ * 12) + g)
                                    : (out + (size_t)b * (N_ * 12) + (g - 12));
        const float* wr = W + ((size_t)i * N_ + j) * N_;
        for (int k = 0; k < N_; ++k)
            acc += wr[k] * src[(size_t)k * 12];
    }
    out[((size_t)b * N_ + j) * 12 + t] = acc;
}

extern "C" void kernel_launch(void* const* d_in, const int* in_sizes, int n_in,
                              void* d_out, int out_size, void* d_ws, size_t ws_size,
                              hipStream_t stream)
{
    const float* x = (const float*)d_in[0];
    const float* W = (const float*)d_in[1];
    float* out = (float*)d_out;

    if (ws_size < WS_NEEDED) {                  // fallback: correct but slow
        for (int t = 0; t < 12; ++t)
            naive_step<<<1024, 256, 0, stream>>>(x, W, out, t);
        return;
    }

    char* Wp = (char*)d_ws;
    char* H  = Wp + WPK_BYTES;
    _Float16* pF  = (_Float16*)(H + H_BYTES);
    _Float16* pFB = (_Float16*)(H + H_BYTES + PF_BYTES);

    prep_all<<<6272, 256, 0, stream>>>(x, W, Wp, H);
    gemm_F<<<2304, 256, 0, stream>>>(Wp, H, pF);
    reduce_step<<<256, 256, 0, stream>>>(pF, pFB, out, H, 0);
    for (int t = 1; t < 12; ++t) {
        gemm_FB<<<64 * t, 256, 0, stream>>>(Wp, H, pFB, t);
        reduce_step<<<256, 256, 0, stream>>>(pF, pFB, out, H, t);
    }
}